// Round 1
// baseline (1781.919 us; speedup 1.0000x reference)
//
#include <hip/hip_runtime.h>

// Problem constants (from reference): B=8, L=4096, D=1024, window W=128
constexpr int kL  = 4096;
constexpr int kD  = 1024;
constexpr int kW  = 128;
constexpr int kDT = 32;    // columns per block
constexpr int kNWB = 2;    // windows per block
constexpr int kROWS = kNWB * kW + kDT;  // 287 needed, pad to 288
// band LDS = 288 * 32 * 4 = 36,864 B

__global__ __launch_bounds__(64) void SWD20_sortwin_kernel(
    const float* __restrict__ v, float* __restrict__ out) {
    __shared__ float band[kROWS * kDT];

    const int tid = threadIdx.x;
    const int d0  = blockIdx.x * kDT;
    const int w0  = blockIdx.y * kNWB;
    const int b   = blockIdx.z;

    const size_t base = (size_t)b * kL * kD;
    // lowest absolute row needed: w0*W - (d0 + DT - 1)
    const int r_lo = w0 * kW - d0 - (kDT - 1);

    // ---- stage band: kROWS rows x kDT cols, coalesced float4 ----
    // total float4 = kROWS*kDT/4 = 2304 -> 36 iters of 64 lanes
    #pragma unroll
    for (int it = 0; it < (kROWS * kDT / 4) / 64; ++it) {
        const int c  = it * 64 + tid;      // float4 index within band
        const int s  = c >> 3;             // band row (kDT/4 = 8 float4 per row)
        const int fo = (c & 7) << 2;       // float offset within row
        const int gr = (r_lo + s + kL) & (kL - 1);
        const float4 val4 = *reinterpret_cast<const float4*>(
            v + base + (size_t)gr * kD + d0 + fo);
        *reinterpret_cast<float4*>(&band[c * 4]) = val4;
    }
    __syncthreads();

    // ---- extract this thread's shifted 128-element window ----
    const int wl = tid >> 5;               // which window (0..1)
    const int dl = tid & 31;               // which column within tile
    const int sbase = wl * kW + (kDT - 1) - dl;

    float val[kW];
    #pragma unroll
    for (int i = 0; i < kW; ++i)
        val[i] = band[(sbase + i) * kDT + dl];

    // ---- bitonic sort, 128 elements ascending, fully unrolled ----
    #pragma unroll
    for (int k = 2; k <= kW; k <<= 1) {
        #pragma unroll
        for (int j = k >> 1; j > 0; j >>= 1) {
            #pragma unroll
            for (int i = 0; i < kW; ++i) {
                const int ij = i ^ j;
                if (ij > i) {
                    const bool up = ((i & k) == 0);
                    const float a = val[i], c = val[ij];
                    const float lo = fminf(a, c), hi = fmaxf(a, c);
                    val[i]  = up ? lo : hi;
                    val[ij] = up ? hi : lo;
                }
            }
        }
    }

    // ---- direct store: at fixed i, lanes write 2 contiguous 128B segments ----
    float* op = out + base + ((size_t)(w0 + wl) * kW) * kD + d0 + dl;
    #pragma unroll
    for (int i = 0; i < kW; ++i)
        op[(size_t)i * kD] = val[i];
}

extern "C" void kernel_launch(void* const* d_in, const int* in_sizes, int n_in,
                              void* d_out, int out_size, void* d_ws, size_t ws_size,
                              hipStream_t stream) {
    const float* v = (const float*)d_in[2];   // inputs: q, k, v — only v used
    float* out = (float*)d_out;
    const int B = in_sizes[2] / (kL * kD);    // = 8
    dim3 grid(kD / kDT, (kL / kW) / kNWB, B); // 32 x 16 x 8 = 4096 blocks
    dim3 block(64);
    hipLaunchKernelGGL(SWD20_sortwin_kernel, grid, block, 0, stream, v, out);
}

// Round 2
// 1776.973 us; speedup vs baseline: 1.0028x; 1.0028x over previous
//
#include <hip/hip_runtime.h>

// Problem constants (from reference): B=8, L=4096, D=1024, window W=128
constexpr int kL  = 4096;
constexpr int kD  = 1024;
constexpr int kW  = 128;
constexpr int kDT = 32;    // columns per block
constexpr int kNWB = 2;    // windows per block
constexpr int kROWS = kNWB * kW + kDT;  // 287 needed, pad to 288
// band LDS = 288 * 32 * 4 = 36,864 B

// __launch_bounds__(64, 1): min 1 wave/EU -> VGPR budget up to 512, so the
// 128-float sort array stays in registers (132-VGPR spill was R1's 28x
// write amplification).
__global__ __launch_bounds__(64, 1) void SWD20_sortwin_kernel(
    const float* __restrict__ v, float* __restrict__ out) {
    __shared__ float band[kROWS * kDT];

    const int tid = threadIdx.x;
    const int d0  = blockIdx.x * kDT;
    const int w0  = blockIdx.y * kNWB;
    const int b   = blockIdx.z;

    const size_t base = (size_t)b * kL * kD;
    // lowest absolute row needed: w0*W - (d0 + DT - 1)
    const int r_lo = w0 * kW - d0 - (kDT - 1);

    // ---- stage band: kROWS rows x kDT cols, coalesced float4 ----
    // total float4 = kROWS*kDT/4 = 2304 -> 36 iters of 64 lanes
    #pragma unroll
    for (int it = 0; it < (kROWS * kDT / 4) / 64; ++it) {
        const int c  = it * 64 + tid;      // float4 index within band
        const int s  = c >> 3;             // band row (kDT/4 = 8 float4 per row)
        const int fo = (c & 7) << 2;       // float offset within row
        const int gr = (r_lo + s + kL) & (kL - 1);
        const float4 val4 = *reinterpret_cast<const float4*>(
            v + base + (size_t)gr * kD + d0 + fo);
        *reinterpret_cast<float4*>(&band[c * 4]) = val4;
    }
    __syncthreads();

    // ---- extract this thread's shifted 128-element window ----
    const int wl = tid >> 5;               // which window (0..1)
    const int dl = tid & 31;               // which column within tile
    const int sbase = wl * kW + (kDT - 1) - dl;

    float val[kW];
    #pragma unroll
    for (int i = 0; i < kW; ++i)
        val[i] = band[(sbase + i) * kDT + dl];

    // ---- bitonic sort, 128 elements ascending, fully unrolled ----
    #pragma unroll
    for (int k = 2; k <= kW; k <<= 1) {
        #pragma unroll
        for (int j = k >> 1; j > 0; j >>= 1) {
            #pragma unroll
            for (int i = 0; i < kW; ++i) {
                const int ij = i ^ j;
                if (ij > i) {
                    const bool up = ((i & k) == 0);
                    const float a = val[i], c = val[ij];
                    const float lo = fminf(a, c), hi = fmaxf(a, c);
                    val[i]  = up ? lo : hi;
                    val[ij] = up ? hi : lo;
                }
            }
        }
    }

    // ---- direct store: at fixed i, lanes write 2 contiguous 128B segments ----
    float* op = out + base + ((size_t)(w0 + wl) * kW) * kD + d0 + dl;
    #pragma unroll
    for (int i = 0; i < kW; ++i)
        op[(size_t)i * kD] = val[i];
}

extern "C" void kernel_launch(void* const* d_in, const int* in_sizes, int n_in,
                              void* d_out, int out_size, void* d_ws, size_t ws_size,
                              hipStream_t stream) {
    const float* v = (const float*)d_in[2];   // inputs: q, k, v — only v used
    float* out = (float*)d_out;
    const int B = in_sizes[2] / (kL * kD);    // = 8
    dim3 grid(kD / kDT, (kL / kW) / kNWB, B); // 32 x 16 x 8 = 4096 blocks
    dim3 block(64);
    hipLaunchKernelGGL(SWD20_sortwin_kernel, grid, block, 0, stream, v, out);
}

// Round 3
// 66.604 us; speedup vs baseline: 26.7538x; 26.6796x over previous
//
#include <hip/hip_runtime.h>

// Problem constants (from reference): B=8, L=4096, D=1024, window W=128
constexpr int kL  = 4096;
constexpr int kD  = 1024;
constexpr int kW  = 128;
constexpr int kDT = 32;    // columns per block
constexpr int kNWB = 2;    // windows per block
constexpr int kROWS = kNWB * kW + kDT;  // 287 needed, pad to 288
// band LDS = 288 * 32 * 4 = 36,864 B

// Bitonic network with K, J as TEMPLATE constants. This guarantees that after
// the single-level i-loop unrolls, every val[] index is a parse-time constant,
// so SROA promotes the 128-float array to VGPRs. (R1/R2 failure: runtime j in
// `val[i^j]` -> alloca stays in scratch -> 3.5 GB spill traffic.)
template<int K, int J>
__device__ __forceinline__ void bitonic_stage(float (&val)[kW]) {
    #pragma unroll
    for (int i = 0; i < kW; ++i) {
        const int ij = i ^ J;
        if (ij > i) {
            const bool up = ((i & K) == 0);
            const float a = val[i], c = val[ij];
            const float lo = fminf(a, c), hi = fmaxf(a, c);
            val[i]  = up ? lo : hi;
            val[ij] = up ? hi : lo;
        }
    }
    if constexpr (J > 1)       bitonic_stage<K, J / 2>(val);
    else if constexpr (K < kW) bitonic_stage<K * 2, K>(val);
}

__global__ __launch_bounds__(64, 1) void SWD20_sortwin_kernel(
    const float* __restrict__ v, float* __restrict__ out) {
    __shared__ float band[kROWS * kDT];

    const int tid = threadIdx.x;
    const int d0  = blockIdx.x * kDT;
    const int w0  = blockIdx.y * kNWB;
    const int b   = blockIdx.z;

    const size_t base = (size_t)b * kL * kD;
    // lowest absolute row needed: w0*W - (d0 + DT - 1)
    const int r_lo = w0 * kW - d0 - (kDT - 1);

    // ---- stage band: kROWS rows x kDT cols, coalesced float4 ----
    // total float4 = kROWS*kDT/4 = 2304 -> 36 iters of 64 lanes
    #pragma unroll
    for (int it = 0; it < (kROWS * kDT / 4) / 64; ++it) {
        const int c  = it * 64 + tid;      // float4 index within band
        const int s  = c >> 3;             // band row (kDT/4 = 8 float4 per row)
        const int fo = (c & 7) << 2;       // float offset within row
        const int gr = (r_lo + s + kL) & (kL - 1);
        const float4 val4 = *reinterpret_cast<const float4*>(
            v + base + (size_t)gr * kD + d0 + fo);
        *reinterpret_cast<float4*>(&band[c * 4]) = val4;
    }
    __syncthreads();

    // ---- extract this thread's shifted 128-element window ----
    const int wl = tid >> 5;               // which window (0..1)
    const int dl = tid & 31;               // which column within tile
    const int sbase = wl * kW + (kDT - 1) - dl;

    float val[kW];
    #pragma unroll
    for (int i = 0; i < kW; ++i)
        val[i] = band[(sbase + i) * kDT + dl];

    // ---- bitonic sort, 128 elements ascending, fully in registers ----
    bitonic_stage<2, 1>(val);

    // ---- direct store: at fixed i, lanes write 2 contiguous 128B segments ----
    float* op = out + base + ((size_t)(w0 + wl) * kW) * kD + d0 + dl;
    #pragma unroll
    for (int i = 0; i < kW; ++i)
        op[(size_t)i * kD] = val[i];
}

extern "C" void kernel_launch(void* const* d_in, const int* in_sizes, int n_in,
                              void* d_out, int out_size, void* d_ws, size_t ws_size,
                              hipStream_t stream) {
    const float* v = (const float*)d_in[2];   // inputs: q, k, v — only v used
    float* out = (float*)d_out;
    const int B = in_sizes[2] / (kL * kD);    // = 8
    dim3 grid(kD / kDT, (kL / kW) / kNWB, B); // 32 x 16 x 8 = 4096 blocks
    dim3 block(64);
    hipLaunchKernelGGL(SWD20_sortwin_kernel, grid, block, 0, stream, v, out);
}